// Round 11
// baseline (380.825 us; speedup 1.0000x reference)
//
#include <hip/hip_runtime.h>

// ---------------------------------------------------------------------------
// GraphEncoder: B=32 x N=128, E=128, H=8, DH=16, L=4, M=16384 edges.
// Round 11: round-7 structure with k_edge Bs-staging fix (i<4 -> i<8;
//   only rows 0-63 of the 128-row Wc tile were staged -> uninit LDS -> NaN).
// (a) direct-MFMA edge kernel replaces tbuild+contract+48MB T.
// (b) launch fusion: LN+QKV0 -> k_lnqkv; layerout + next-layer QKV tail;
//   dist folded into k_setup. Dispatches 18 -> 12.
// ---------------------------------------------------------------------------

typedef __attribute__((ext_vector_type(8))) short bf16x8;
typedef __attribute__((ext_vector_type(4))) float f32x4;
#define MFMA16(a, b, c) __builtin_amdgcn_mfma_f32_16x16x32_bf16(a, b, c, 0, 0, 0)

__device__ inline unsigned short f2bf(float f) {          // RTNE
  unsigned u = __float_as_uint(f);
  u = (u + 0x7FFF + ((u >> 16) & 1)) >> 16;
  return (unsigned short)u;
}
__device__ inline unsigned pack2(float a, float b) {
  return (unsigned)f2bf(a) | ((unsigned)f2bf(b) << 16);
}

// ---------------------------------------------------------------------------
// k_setup: blocks 0..2047 = node_proj (2 nodes/block); 2048..14335 = flat
// segments: zero agg | rbf | wb | qkvt+qkvb | wot | w1t | w2t | dist
// ---------------------------------------------------------------------------
__global__ __launch_bounds__(256) void k_setup(
    const float* __restrict__ x, const float* __restrict__ Wproj,
    const float* __restrict__ bproj, float* __restrict__ h,
    unsigned short* __restrict__ hb,
    const float* __restrict__ ea, float* __restrict__ ea2,
    const float* __restrict__ Wlin, const float* __restrict__ blin,
    unsigned short* __restrict__ wb,
    const float* __restrict__ Wq, const float* __restrict__ Wk,
    const float* __restrict__ Wv, const float* __restrict__ bq,
    const float* __restrict__ bk, const float* __restrict__ bv,
    unsigned short* __restrict__ qkvt, float* __restrict__ qkvb,
    const float* __restrict__ Wo, unsigned short* __restrict__ wot,
    const float* __restrict__ W1, unsigned short* __restrict__ w1t,
    const float* __restrict__ W2, unsigned short* __restrict__ w2t,
    float* __restrict__ agg,
    const float* __restrict__ pos, float* __restrict__ db) {
  __shared__ float xs[2][64];
  int blk = blockIdx.x, t = threadIdx.x;
  if (blk < 2048) {                       // ---- node projection ----
    int sub = t >> 7, e = t & 127;
    int n = blk * 2 + sub;
    if (e < 64) xs[sub][e] = x[n * 64 + e];
    __syncthreads();
    float acc = bproj[e];
#pragma unroll
    for (int a = 0; a < 64; a++) acc += xs[sub][a] * Wproj[a * 128 + e];
    h[n * 128 + e] = acc;
    hb[n * 128 + e] = f2bf(acc);
    return;
  }
  int idx = (blk - 2048) * 256 + t;       // 0 .. 3145727
  if (idx < 524288) { agg[idx] = 0.0f; return; }
  idx -= 524288;
  if (idx < 786432) {                     // ---- rbf/ea2 ----
    int m = idx / 48, c = idx % 48;
    float v;
    if (c < 15) {
      v = ea[m * 16 + c];
    } else if (c < 47) {
      int i = c - 15;
      float d = fminf(10.0f, fmaxf(0.0f, ea[m * 16 + 15]));
      float diff = d - 5.0f * (float)i / 31.0f;
      v = __expf(-38.44f * diff * diff);
    } else {
      v = 1.0f;
    }
    ea2[m * 48 + c] = v;
    return;
  }
  idx -= 786432;
  if (idx < 786432) {                     // ---- wb (Wlin+blin bf16) ----
    float v = (idx < 770048) ? Wlin[idx] : blin[idx - 770048];
    wb[idx] = f2bf(v);
    return;
  }
  idx -= 786432;
  if (idx < 196608) {                     // ---- qkvt + qkvb ----
    int l = idx / 49152, r = idx % 49152;
    int j = r / 128, a = r % 128;
    int jj = j & 127;
    const float* W = (j < 128) ? Wq : (j < 256) ? Wk : Wv;
    qkvt[idx] = f2bf(W[l * 16384 + a * 128 + jj]);
    if (a == 0) {
      const float* bb = (j < 128) ? bq : (j < 256) ? bk : bv;
      qkvb[l * 384 + j] = bb[l * 128 + jj];
    }
    return;
  }
  idx -= 196608;
  if (idx < 65536) {                      // ---- wot [l][128out][128k] ----
    int l = idx / 16384, r = idx % 16384;
    int a = r / 128, j = r % 128;
    wot[l * 16384 + j * 128 + a] = f2bf(Wo[idx]);
    return;
  }
  idx -= 65536;
  if (idx < 131072) {                     // ---- w1t [l][256out][128k] ----
    int l = idx / 32768, r = idx % 32768;
    int a = r / 256, j = r % 256;
    w1t[l * 32768 + j * 128 + a] = f2bf(W1[idx]);
    return;
  }
  idx -= 131072;
  if (idx < 131072) {                     // ---- w2t [l][128out][256k] ----
    int l = idx / 32768, r = idx % 32768;
    int a = r / 128, j = r % 128;
    w2t[l * 32768 + j * 256 + a] = f2bf(W2[idx]);
    return;
  }
  idx -= 131072;
  {                                       // ---- dist: db[b][i][j] ----
    int j = idx & 127, i2 = (idx >> 7) & 127, b = idx >> 14;
    float x0 = pos[(b * 128 + i2) * 3 + 0];
    float y0 = pos[(b * 128 + i2) * 3 + 1];
    float z0 = pos[(b * 128 + i2) * 3 + 2];
    float dx = x0 - pos[(b * 128 + j) * 3 + 0];
    float dy = y0 - pos[(b * 128 + j) * 3 + 1];
    float dz = z0 - pos[(b * 128 + j) * 3 + 2];
    float d2 = dx * dx + dy * dy + dz * dz;
    db[b * 16384 + i2 * 128 + j] = (d2 > 0.0f) ? sqrtf(d2) : 0.0f;
  }
}

// ---------------------------------------------------------------------------
// k_edge: per 64-edge block: msg[m,e] = sum_c ea2[m,c] * (h[src_m] @ Wc^T)[e]
// MFMA per c seeded with zero C; VALU scale-accumulate; atomic scatter.
// ---------------------------------------------------------------------------
__global__ __launch_bounds__(256) void k_edge(const float* __restrict__ ea2,
    const int* __restrict__ ei, const unsigned short* __restrict__ hbf,
    const unsigned short* __restrict__ wb, float* __restrict__ agg) {
  __shared__ unsigned short hs[8192];    // [64][128] bf16 swizzled (16KB)
  __shared__ float et[64][48];           // ea2 tile (12KB)
  __shared__ unsigned short Bs[16384];   // Wc [128e][128f] swizzled (32KB)
  __shared__ int srcs[64], dsts[64];
  int t = threadIdx.x, m0 = blockIdx.x * 64;
  if (t < 64) { srcs[t] = ei[16384 + m0 + t]; dsts[t] = ei[m0 + t]; }
  __syncthreads();
  uint4* hs4 = (uint4*)hs;
#pragma unroll
  for (int i = 0; i < 4; i++) {          // hs: 64 rows x 16 chunks = 1024
    int q = t + i * 256;
    int row = q >> 4, ch = q & 15;
    hs4[row * 16 + (ch ^ (row & 7))] = ((const uint4*)(hbf + (size_t)srcs[row] * 128))[ch];
  }
#pragma unroll
  for (int i = 0; i < 12; i++) {         // 64*48 floats
    int p = t + i * 256;
    int mi = p / 48, c = p % 48;
    et[mi][c] = ea2[(size_t)(m0 + mi) * 48 + c];
  }
  int w = t >> 6, l = t & 63, lr = l & 15, lg = l >> 4;
  float msg[2][4][4] = {};               // [e-half][m-frag][reg]
  const f32x4 zf = {0.f, 0.f, 0.f, 0.f};
  uint4* Bs4 = (uint4*)Bs;
  for (int c = 0; c < 48; c++) {
    __syncthreads();                     // hs/et ready (c=0); Bs reads done (c>0)
#pragma unroll
    for (int i = 0; i < 8; i++) {        // Bs: 128 rows x 16 chunks = 2048 (FIX: was 4 -> half-staged)
      int q = t + i * 256;
      int row = q >> 4, ch = q & 15;
      Bs4[row * 16 + (ch ^ (row & 7))] =
          ((const uint4*)(wb + (size_t)c * 16384 + row * 128))[ch];
    }
    __syncthreads();
    f32x4 pacc[2][4];
#pragma unroll
    for (int s = 0; s < 4; s++) {
      bf16x8 af[2];
#pragma unroll
      for (int e2 = 0; e2 < 2; e2++) {
        int er = w * 32 + e2 * 16 + lr;
        int ch = (s * 4 + lg) ^ (er & 7);
        af[e2] = *(const bf16x8*)&Bs[(er * 16 + ch) * 8];
      }
#pragma unroll
      for (int n = 0; n < 4; n++) {
        int nr = n * 16 + lr;
        int ch = (s * 4 + lg) ^ (nr & 7);
        bf16x8 bfr = *(const bf16x8*)&hs[(nr * 16 + ch) * 8];
        if (s == 0) {
          pacc[0][n] = MFMA16(af[0], bfr, zf);
          pacc[1][n] = MFMA16(af[1], bfr, zf);
        } else {
          pacc[0][n] = MFMA16(af[0], bfr, pacc[0][n]);
          pacc[1][n] = MFMA16(af[1], bfr, pacc[1][n]);
        }
      }
    }
#pragma unroll
    for (int n = 0; n < 4; n++) {
      float am = et[n * 16 + lr][c];     // broadcast within lane-groups
#pragma unroll
      for (int e2 = 0; e2 < 2; e2++)
#pragma unroll
        for (int r = 0; r < 4; r++)
          msg[e2][n][r] += am * pacc[e2][n][r];
    }
  }
#pragma unroll
  for (int n = 0; n < 4; n++) {
    int dst = dsts[n * 16 + lr];
#pragma unroll
    for (int e2 = 0; e2 < 2; e2++) {
      int e0 = w * 32 + e2 * 16 + lg * 4;
#pragma unroll
      for (int r = 0; r < 4; r++)
        atomicAdd(&agg[(size_t)dst * 128 + e0 + r], msg[e2][n][r]);
    }
  }
}

// ---------------------------------------------------------------------------
// k_lnqkv: xp = LN(agg + hbuf; g_en,b_en)  then  qkv = xp @ qkvt^T + qkvb
// 64 nodes/block; wave-per-row LN; 3x 128-col MFMA chunks.
// ---------------------------------------------------------------------------
__global__ __launch_bounds__(256) void k_lnqkv(const float* __restrict__ agg,
    const float* __restrict__ hbuf, const float* __restrict__ g_en,
    const float* __restrict__ b_en, float* __restrict__ xp,
    const unsigned short* __restrict__ qkvt, const float* __restrict__ qkvb,
    float* __restrict__ qkv) {
  __shared__ unsigned short As[8192];    // [64][128] bf16 swizzled
  __shared__ unsigned short Bs[16384];
  int t = threadIdx.x, m0 = blockIdx.x * 64;
  int w = t >> 6, l = t & 63, lr = l & 15, lg = l >> 4;
  float ge0 = g_en[2 * l], ge1 = g_en[2 * l + 1];
  float be0 = b_en[2 * l], be1 = b_en[2 * l + 1];
  for (int i = 0; i < 16; i++) {
    int r = i * 4 + w;
    float2 av = ((const float2*)(agg + (size_t)(m0 + r) * 128))[l];
    float2 hv = ((const float2*)(hbuf + (size_t)(m0 + r) * 128))[l];
    float v0 = av.x + hv.x, v1 = av.y + hv.y;
    float s = v0 + v1, s2 = v0 * v0 + v1 * v1;
#pragma unroll
    for (int o = 1; o < 64; o <<= 1) { s += __shfl_xor(s, o); s2 += __shfl_xor(s2, o); }
    float mu = s * (1.0f / 128.0f);
    float var = fmaxf(s2 * (1.0f / 128.0f) - mu * mu, 0.0f);
    float inv = rsqrtf(var + 1e-5f);
    float o0 = (v0 - mu) * inv * ge0 + be0;
    float o1 = (v1 - mu) * inv * ge1 + be1;
    ((float2*)(xp + (size_t)(m0 + r) * 128))[l] = make_float2(o0, o1);
    ((unsigned*)As)[(r * 16 + ((l >> 2) ^ (r & 7))) * 4 + (l & 3)] = pack2(o0, o1);
  }
  uint4* Bs4 = (uint4*)Bs;
  for (int cchunk = 0; cchunk < 3; cchunk++) {
    __syncthreads();
#pragma unroll
    for (int i = 0; i < 8; i++) {
      int q = t + i * 256;
      int row = q >> 4, ch = q & 15;
      Bs4[row * 16 + (ch ^ (row & 7))] =
          ((const uint4*)(qkvt + (size_t)(cchunk * 128 + row) * 128))[ch];
    }
    __syncthreads();
    f32x4 acc[2][4];
#pragma unroll
    for (int e2 = 0; e2 < 2; e2++)
#pragma unroll
      for (int n = 0; n < 4; n++) acc[e2][n] = (f32x4){0.f, 0.f, 0.f, 0.f};
#pragma unroll
    for (int s = 0; s < 4; s++) {
      bf16x8 af[2];
#pragma unroll
      for (int e2 = 0; e2 < 2; e2++) {
        int er = w * 32 + e2 * 16 + lr;
        int ch = (s * 4 + lg) ^ (er & 7);
        af[e2] = *(const bf16x8*)&Bs[(er * 16 + ch) * 8];
      }
#pragma unroll
      for (int n = 0; n < 4; n++) {
        int nr = n * 16 + lr;
        int ch = (s * 4 + lg) ^ (nr & 7);
        bf16x8 bfr = *(const bf16x8*)&As[(nr * 16 + ch) * 8];
        acc[0][n] = MFMA16(af[0], bfr, acc[0][n]);
        acc[1][n] = MFMA16(af[1], bfr, acc[1][n]);
      }
    }
#pragma unroll
    for (int e2 = 0; e2 < 2; e2++) {
      int e0 = cchunk * 128 + w * 32 + e2 * 16 + lg * 4;
      float4 bb = *(const float4*)&qkvb[e0];
#pragma unroll
      for (int n = 0; n < 4; n++) {
        int node = m0 + n * 16 + lr;
        float4 ov;
#pragma unroll
        for (int r = 0; r < 4; r++) ((float*)&ov)[r] = acc[e2][n][r] + ((const float*)&bb)[r];
        *(float4*)&qkv[(size_t)node * 384 + e0] = ov;
      }
    }
  }
}

// attention for one (b,h); qkv packed [node][384] = q|k|v (verified round 5)
__global__ __launch_bounds__(128) void k_attn(const float* __restrict__ qkv,
    const float* __restrict__ db, float* __restrict__ oatt) {
  __shared__ float ks[128][16], vs[128][16];
  int bh = blockIdx.x, b = bh >> 3, h = bh & 7;
  int i = threadIdx.x;
  int node = b * 128 + i;
  const float4* kr = (const float4*)(qkv + (size_t)node * 384 + 128 + h * 16);
  const float4* vr = (const float4*)(qkv + (size_t)node * 384 + 256 + h * 16);
#pragma unroll
  for (int d4 = 0; d4 < 4; d4++) {
    *(float4*)&ks[i][d4 * 4] = kr[d4];
    *(float4*)&vs[i][d4 * 4] = vr[d4];
  }
  float qr[16];
  const float4* qp = (const float4*)(qkv + (size_t)node * 384 + h * 16);
#pragma unroll
  for (int d4 = 0; d4 < 4; d4++) *(float4*)&qr[d4 * 4] = qp[d4];
  __syncthreads();
  const float4* dbr = (const float4*)(db + b * 16384 + i * 128);
  float rsum = 0.0f, o[16] = {};
  for (int j4 = 0; j4 < 32; j4++) {
    float4 dv = dbr[j4];
#pragma unroll
    for (int u = 0; u < 4; u++) {
      int j = j4 * 4 + u;
      float s = 0.0f;
#pragma unroll
      for (int d = 0; d < 16; d++) s += qr[d] * ks[j][d];
      s = s * 0.25f + ((const float*)&dv)[u];
      s = fminf(10.0f, fmaxf(-10.0f, s));
      float p = __expf(s);
      rsum += p;
#pragma unroll
      for (int d = 0; d < 16; d++) o[d] += p * vs[j][d];
    }
  }
  float r = 1.0f / rsum;
  float* op = oatt + (size_t)node * 128 + h * 16;
#pragma unroll
  for (int d4 = 0; d4 < 4; d4++)
    *(float4*)&op[d4 * 4] = make_float4(o[d4 * 4] * r, o[d4 * 4 + 1] * r, o[d4 * 4 + 2] * r, o[d4 * 4 + 3] * r);
}

// ---------------------------------------------------------------------------
// k_loqkv: round-6 layerout (verified) with optional next-layer QKV tail.
// ---------------------------------------------------------------------------
template <int QKV>
__global__ __launch_bounds__(256) void k_loqkv(
    const float* __restrict__ oatt, float* __restrict__ xp,
    const unsigned short* __restrict__ wot, const float* __restrict__ bo,
    const float* __restrict__ g1, const float* __restrict__ b1,
    const unsigned short* __restrict__ w1t, const float* __restrict__ bf1,
    const unsigned short* __restrict__ w2t, const float* __restrict__ bf2,
    const float* __restrict__ g2, const float* __restrict__ b2,
    const unsigned short* __restrict__ qkvtn, const float* __restrict__ qkvbn,
    float* __restrict__ qkv) {
  __shared__ unsigned short ffs[16384];   // [64][32ch][8]; ph1: A-stage
  __shared__ unsigned short x1s[8192];    // [64][16ch][8]; later: xp bf16 stage
  __shared__ unsigned short Bs[16384];
  __shared__ float red[2][4][64];
  int t = threadIdx.x;
  int m0 = blockIdx.x << 6;
  int w = t >> 6, l = t & 63, lr = l & 15, lg = l >> 4;

  // ---- phase 1: Wo GEMM ----
  {
    uint4* a4 = (uint4*)ffs;
#pragma unroll
    for (int i = 0; i < 4; i++) {
      int q = t + i * 256;
      int row = q >> 4, ch = q & 15;
      const float* ap = oatt + (size_t)(m0 + row) * 128 + ch * 8;
      float4 fa = *(const float4*)ap;
      float4 fb = *(const float4*)(ap + 4);
      uint4 pk;
      pk.x = pack2(fa.x, fa.y); pk.y = pack2(fa.z, fa.w);
      pk.z = pack2(fb.x, fb.y); pk.w = pack2(fb.z, fb.w);
      a4[row * 16 + (ch ^ (row & 7))] = pk;
    }
    uint4* b4p = (uint4*)Bs;
#pragma unroll
    for (int i = 0; i < 8; i++) {
      int q = t + i * 256;
      int row = q >> 4, ch = q & 15;
      b4p[row * 16 + (ch ^ (row & 7))] = *((const uint4*)(wot + (size_t)row * 128) + ch);
    }
  }
  __syncthreads();
  f32x4 acc[2][4];
#pragma unroll
  for (int et = 0; et < 2; et++)
#pragma unroll
    for (int n = 0; n < 4; n++) acc[et][n] = (f32x4){0.f, 0.f, 0.f, 0.f};
#pragma unroll
  for (int s = 0; s < 4; s++) {
    bf16x8 af[2];
#pragma unroll
    for (int et = 0; et < 2; et++) {
      int er = w * 32 + et * 16 + lr;
      int ch = (s * 4 + lg) ^ (er & 7);
      af[et] = *(const bf16x8*)&Bs[(er * 16 + ch) * 8];
    }
#pragma unroll
    for (int n = 0; n < 4; n++) {
      int nr = n * 16 + lr;
      int ch = (s * 4 + lg) ^ (nr & 7);
      bf16x8 bfr = *(const bf16x8*)&ffs[(nr * 16 + ch) * 8];
      acc[0][n] = MFMA16(af[0], bfr, acc[0][n]);
      acc[1][n] = MFMA16(af[1], bfr, acc[1][n]);
    }
  }
  // epilogue 1: + bo + xp residual -> LN(g1,b1) -> v1 regs + x1s bf16
  float v1[2][4][4];
  {
    int e0 = w * 32 + lg * 4;
    float4 bo4[2] = { *(const float4*)&bo[e0], *(const float4*)&bo[e0 + 16] };
#pragma unroll
    for (int et = 0; et < 2; et++)
#pragma unroll
      for (int n = 0; n < 4; n++) {
        int node = m0 + n * 16 + lr;
        float4 rv = *(const float4*)&xp[(size_t)node * 128 + e0 + et * 16];
#pragma unroll
        for (int r = 0; r < 4; r++)
          v1[et][n][r] = acc[et][n][r] + ((const float*)&bo4[et])[r] + ((const float*)&rv)[r];
      }
    float s[4], s2[4];
#pragma unroll
    for (int n = 0; n < 4; n++) {
      float a = 0, b2s = 0;
#pragma unroll
      for (int et = 0; et < 2; et++)
#pragma unroll
        for (int r = 0; r < 4; r++) { a += v1[et][n][r]; b2s += v1[et][n][r] * v1[et][n][r]; }
      s[n] = a; s2[n] = b2s;
    }
#pragma unroll
    for (int off = 16; off < 64; off <<= 1)
#pragma unroll
      for (int n = 0; n < 4; n++) { s[n] += __shfl_xor(s[n], off); s2[n] += __shfl_xor(s2[n], off); }
    if (l < 16) {
#pragma unroll
      for (int n = 0; n < 4; n++) { red[0][w][n * 16 + lr] = s[n]; red[1][w][n * 16 + lr] = s2[n]; }
    }
    __syncthreads();
    float4 g4[2] = { *(const float4*)&g1[e0], *(const float4*)&g1[e0 + 16] };
    float4 bb4[2] = { *(const float4*)&b1[e0], *(const float4*)&b1[e0 + 16] };
#pragma unroll
    for (int n = 0; n < 4; n++) {
      int nloc = n * 16 + lr;
      float ts  = red[0][0][nloc] + red[0][1][nloc] + red[0][2][nloc] + red[0][3][nloc];
      float ts2 = red[1][0][nloc] + red[1][1][nloc] + red[1][2][nloc] + red[1][3][nloc];
      float mu = ts * (1.0f / 128.0f);
      float var = fmaxf(ts2 * (1.0f / 128.0f) - mu * mu, 0.0f);
      float inv = rsqrtf(var + 1e-5f);
#pragma unroll
      for (int et = 0; et < 2; et++) {
#pragma unroll
        for (int r = 0; r < 4; r++)
          v1[et][n][r] = (v1[et][n][r] - mu) * inv * ((const float*)&g4[et])[r] + ((const float*)&bb4[et])[r];
        int ch = w * 4 + et * 2 + (lg >> 1);
        uint2 pk;
        pk.x = pack2(v1[et][n][0], v1[et][n][1]);
        pk.y = pack2(v1[et][n][2], v1[et][n][3]);
        *(uint2*)&x1s[(nloc * 16 + (ch ^ (nloc & 7))) * 8 + (lg & 1) * 4] = pk;
      }
    }
  }
  __syncthreads();

  // ---- phase 2: FFN1 (two 128-col tiles), relu -> ffs ----
  for (int ct = 0; ct < 2; ct++) {
    if (ct) __syncthreads();
    uint4* b4p = (uint4*)Bs;
#pragma unroll
    for (int i = 0; i < 8; i++) {
      int q = t + i * 256;
      int row = q >> 4, ch = q & 15;
      b4p[row * 16 + (ch ^ (row & 7))] =
          *((const uint4*)(w1t + (size_t)(ct * 128 + row) * 128) + ch);
    }
    __syncthreads();
#pragma unroll
    for (int et = 0; et < 2; et++)
#pragma unroll
      for (int n = 0; n < 4; n++) acc[et][n] = (f32x4){0.f, 0.f, 0.f, 0.f};
#pragma unroll
    for (int s = 0; s < 4; s++) {
      bf16x8 af[2];
#pragma unroll
      for (int et = 0; et < 2; et++) {
        int er = w * 32 + et * 16 + lr;
        int ch = (s * 4 + lg) ^ (er & 7);
        af[et] = *(const bf16x8*)&Bs[(er * 16 + ch) * 8];
      }
#pragma unroll
      for (int n = 0; n < 4; n++) {
        int nr = n * 16 + lr;
        int ch = (s * 4 + lg) ^ (nr & 7);
        bf16x8 bfr = *(const bf16x8*)&x1s[(nr * 16 + ch) * 8];
        acc[0][n] = MFMA16(af[0], bfr, acc[0][n]);
        acc[1][n] = MFMA16(af[1], bfr, acc[1][n]);
      }
    }
    int e0 = w * 32 + lg * 4;
    float4 bb0 = *(const float4*)&bf1[ct * 128 + e0];
    float4 bb1 = *(const float4*)&bf1[ct * 128 + e0 + 16];
#pragma unroll
    for (int et = 0; et < 2; et++) {
      const float* bbp = et ? (const float*)&bb1 : (const float*)&bb0;
#pragma unroll
      for (int n = 0; n < 4; n++) {
        int nloc = n * 16 + lr;
        float f0 = fmaxf(acc[et][n][0] + bbp[0], 0.0f);
        float f1 = fmaxf(acc[et][n][1] + bbp[1], 0.0f);
        float f2 = fmaxf(acc[et][n][2] + bbp[2], 0.0f);
        float f3 = fmaxf(acc[et][n][3] + bbp[3], 0.0f);
        int cg = ct * 16 + w * 4 + et * 2 + (lg >> 1);
        uint2 pk;
        pk.x = pack2(f0, f1);
        pk.y = pack2(f2, f3);
        *(uint2*)&ffs[(nloc * 32 + (cg ^ (nloc & 7))) * 8 + (lg & 1) * 4] = pk;
      }
    }
  }
  __syncthreads();

  // ---- phase 3: FFN2 (K=256) + bf2 + x1 res + LN(g2,b2) -> xp (+x1s pack) --
  f32x4 acc3[2][4];
#pragma unroll
  for (int et = 0; et < 2; et++)
#pragma unroll
    for (int n = 0; n < 4; n++) acc3[et][n] = (f32x4){0.f, 0.f, 0.f, 0.f};
  for (int kc = 0; kc < 2; kc++) {
    if (kc) __syncthreads();
    uint4* b4p = (uint4*)Bs;
#pragma unroll
    for (int i = 0; i < 8; i++) {
      int q = t + i * 256;
      int row = q >> 4, ch = q & 15;
      b4p[row * 16 + (ch ^ (row & 7))] =
          *((const uint4*)(w2t + (size_t)row * 256 + kc * 128) + ch);
    }
    __syncthreads();
#pragma unroll
    for (int s = 0; s < 4; s++) {
      bf16x8 af[2];
#pragma unroll
      for (int et = 0; et < 2; et++) {
        int er = w * 32 + et * 16 + lr;
        int ch = (s * 4 + lg) ^ (er & 7);
        af[et] = *(const bf16x8*)&Bs[(er * 16 + ch) * 8];
      }
#pragma unroll
      for (int n = 0; n < 4; n++) {
        int nr = n * 16 + lr;
        int gch = kc * 16 + s * 4 + lg;
        bf16x8 bfr = *(const bf16x8*)&ffs[(nr * 32 + (gch ^ (nr & 7))) * 8];
        acc3[0][n] = MFMA16(af[0], bfr, acc3[0][n]);
        acc3[1][n] = MFMA16(af[1], bfr, acc3[1][n]);
      }
    }
  }
  {
    int e0 = w * 32 + lg * 4;
    float4 bo4[2] = { *(const float4*)&bf2[e0], *(const float4*)&bf2[e0 + 16] };
    float v2[2][4][4];
#pragma unroll
    for (int et = 0; et < 2; et++)
#pragma unroll
      for (int n = 0; n < 4; n++)
#pragma unroll
        for (int r = 0; r < 4; r++)
          v2[et][n][r] = acc3[et][n][r] + ((const float*)&bo4[et])[r] + v1[et][n][r];
    float s[4], s2[4];
#pragma unroll
    for (int n = 0; n < 4; n++) {
      float a = 0, b2s = 0;
#pragma unroll
      for (int et = 0; et < 2; et++)
#pragma unroll
        for (int r = 0; r < 4; r++) { a += v2[et][n][r]; b2s += v2[et][n][r] * v2[et][n][r]; }
      s[n] = a; s2[n] = b2s;
    }
#pragma unroll
    for (int off = 16; off < 64; off <<= 1)
#pragma unroll
      for (int n = 0; n < 4; n++) { s[n] += __shfl_xor(s[n], off); s2[n] += __shfl_xor(s2[n], off); }
    __syncthreads();
    if (l < 16) {
#pragma unroll
      for (int n = 0; n < 4; n++) { red[0][w][n * 16 + lr] = s[n]; red[1][w][n * 16 + lr] = s2[n]; }
    }
    __syncthreads();
    float4 g4[2] = { *(const float4*)&g2[e0], *(const float4*)&g2[e0 + 16] };
    float4 bb4[2] = { *(const float4*)&b2[e0], *(const float4*)&b2[e0 + 16] };
#pragma unroll
    for (int n = 0; n < 4; n++) {
      int nloc = n * 16 + lr;
      float ts  = red[0][0][nloc] + red[0][1][nloc] + red[0][2][nloc] + red[0][3][nloc];
      float ts2 = red[1][0][nloc] + red[1][1][nloc] + red[1][2][nloc] + red[1][3][nloc];
      float mu = ts * (1.0f / 128.0f);
      float var = fmaxf(ts2 * (1.0f / 128.0f) - mu * mu, 0.0f);
      float inv = rsqrtf(var + 1e-5f);
      int node = m0 + nloc;
#pragma unroll
      for (int et = 0; et < 2; et++) {
        float4 ov;
#pragma unroll
        for (int r = 0; r < 4; r++)
          ((float*)&ov)[r] = (v2[et][n][r] - mu) * inv * ((const float*)&g4[et])[r] + ((const float*)&bb4[et])[r];
        *(float4*)&xp[(size_t)node * 128 + e0 + et * 16] = ov;
        if (QKV) {
          int ch = w * 4 + et * 2 + (lg >> 1);
          uint2 pk;
          pk.x = pack2(((float*)&ov)[0], ((float*)&ov)[1]);
          pk.y = pack2(((float*)&ov)[2], ((float*)&ov)[3]);
          *(uint2*)&x1s[(nloc * 16 + (ch ^ (nloc & 7))) * 8 + (lg & 1) * 4] = pk;
        }
      }
    }
  }

  if (QKV) {
    // ---- phase 4: next-layer QKV from x1s (xp bf16) ----
    uint4* Bs4 = (uint4*)Bs;
    for (int cchunk = 0; cchunk < 3; cchunk++) {
      __syncthreads();
#pragma unroll
      for (int i = 0; i < 8; i++) {
        int q = t + i * 256;
        int row = q >> 4, ch = q & 15;
        Bs4[row * 16 + (ch ^ (row & 7))] =
            ((const uint4*)(qkvtn + (size_t)(cchunk * 128 + row) * 128))[ch];
      }
      __syncthreads();
      f32x4 qa[2][4];
#pragma unroll
      for (int e2 = 0; e2 < 2; e2++)
#pragma unroll
        for (int n = 0; n < 4; n++) qa[e2][n] = (f32x4){0.f, 0.f, 0.f, 0.f};
#pragma unroll
      for (int s = 0; s < 4; s++) {
        bf16x8 af[2];
#pragma unroll
        for (int e2 = 0; e2 < 2; e2++) {
          int er = w * 32 + e2 * 16 + lr;
          int ch = (s * 4 + lg) ^ (er & 7);
          af[e2] = *(const bf16x8*)&Bs[(er * 16 + ch) * 8];
        }
#pragma unroll
        for (int n = 0; n < 4; n++) {
          int nr = n * 16 + lr;
          int ch = (s * 4 + lg) ^ (nr & 7);
          bf16x8 bfr = *(const bf16x8*)&x1s[(nr * 16 + ch) * 8];
          qa[0][n] = MFMA16(af[0], bfr, qa[0][n]);
          qa[1][n] = MFMA16(af[1], bfr, qa[1][n]);
        }
      }
#pragma unroll
      for (int e2 = 0; e2 < 2; e2++) {
        int e0 = cchunk * 128 + w * 32 + e2 * 16 + lg * 4;
        float4 bb = *(const float4*)&qkvbn[e0];
#pragma unroll
        for (int n = 0; n < 4; n++) {
          int node = m0 + n * 16 + lr;
          float4 ov;
#pragma unroll
          for (int r = 0; r < 4; r++) ((float*)&ov)[r] = qa[e2][n][r] + ((const float*)&bb)[r];
          *(float4*)&qkv[(size_t)node * 384 + e0] = ov;
        }
      }
    }
  }
}

__global__ __launch_bounds__(128) void k_pool(const float* __restrict__ xp, float* __restrict__ out) {
  int b = blockIdx.x, e = threadIdx.x;
  float s = 0.0f;
  for (int n = 0; n < 128; n++) s += xp[(b * 128 + n) * 128 + e];
  out[b * 128 + e] = s * (1.0f / 128.0f);
}

extern "C" void kernel_launch(void* const* d_in, const int* in_sizes, int n_in,
                              void* d_out, int out_size, void* d_ws, size_t ws_size,
                              hipStream_t stream) {
  const float* x     = (const float*)d_in[0];
  const int*   ei    = (const int*)  d_in[1];
  const float* ea    = (const float*)d_in[2];
  const float* pos   = (const float*)d_in[3];
  const float* Wproj = (const float*)d_in[5];
  const float* bproj = (const float*)d_in[6];
  const float* Wlin  = (const float*)d_in[7];
  const float* blin  = (const float*)d_in[8];
  const float* g_en  = (const float*)d_in[9];
  const float* b_en  = (const float*)d_in[10];
  const float* Wq    = (const float*)d_in[11];
  const float* Wk    = (const float*)d_in[12];
  const float* Wv    = (const float*)d_in[13];
  const float* Wo    = (const float*)d_in[14];
  const float* bq    = (const float*)d_in[15];
  const float* bk    = (const float*)d_in[16];
  const float* bv    = (const float*)d_in[17];
  const float* bo    = (const float*)d_in[18];
  const float* g1    = (const float*)d_in[19];
  const float* b1    = (const float*)d_in[20];
  const float* W1    = (const float*)d_in[21];
  const float* bf1   = (const float*)d_in[22];
  const float* W2    = (const float*)d_in[23];
  const float* bf2   = (const float*)d_in[24];
  const float* g2    = (const float*)d_in[25];
  const float* b2    = (const float*)d_in[26];

  float* ws = (float*)d_ws;
  float* ea2  = ws;                                         // 786432 f
  float* hbuf = ea2  + 786432;                              // 524288 f
  float* agg  = hbuf + 524288;                              // 524288 f
  unsigned short* hbf  = (unsigned short*)(agg + 524288);   // 524288 us
  unsigned short* wbf  = hbf + 524288;                      // 786432 us
  unsigned short* qkvt = wbf + 786432;                      // 196608 us
  unsigned short* wot  = qkvt + 196608;                     // 65536 us
  unsigned short* w1t  = wot + 65536;                       // 131072 us
  unsigned short* w2t  = w1t + 131072;                      // 131072 us
  float* qkvb = (float*)(w2t + 131072);                     // 1536 f
  float* db   = qkvb + 1536;                                // 524288 f
  float* xp   = db   + 524288;                              // 524288 f
  float* qkv  = xp   + 524288;                              // 1572864 f
  float* oatt = qkv  + 1572864;                             // 524288 f

  k_setup<<<14336, 256, 0, stream>>>(x, Wproj, bproj, hbuf, hbf,
      ea, ea2, Wlin, blin, wbf, Wq, Wk, Wv, bq, bk, bv, qkvt, qkvb,
      Wo, wot, W1, w1t, W2, w2t, agg, pos, db);
  k_edge<<<256, 256, 0, stream>>>(ea2, ei, hbf, wbf, agg);
  k_lnqkv<<<64, 256, 0, stream>>>(agg, hbuf, g_en, b_en, xp, qkvt, qkvb, qkv);

  for (int l = 0; l < 4; l++) {
    k_attn<<<256, 128, 0, stream>>>(qkv, db, oatt);
    if (l < 3) {
      k_loqkv<1><<<64, 256, 0, stream>>>(oatt, xp,
          wot + l * 16384, bo + l * 128, g1 + l * 128, b1 + l * 128,
          w1t + l * 32768, bf1 + l * 256,
          w2t + l * 32768, bf2 + l * 128, g2 + l * 128, b2 + l * 128,
          qkvt + (l + 1) * 49152, qkvb + (l + 1) * 384, qkv);
    } else {
      k_loqkv<0><<<64, 256, 0, stream>>>(oatt, xp,
          wot + l * 16384, bo + l * 128, g1 + l * 128, b1 + l * 128,
          w1t + l * 32768, bf1 + l * 256,
          w2t + l * 32768, bf2 + l * 128, g2 + l * 128, b2 + l * 128,
          nullptr, nullptr, nullptr);
    }
  }

  k_pool<<<32, 128, 0, stream>>>(xp, (float*)d_out);
}

// Round 13
// 341.794 us; speedup vs baseline: 1.1142x; 1.1142x over previous
//
#include <hip/hip_runtime.h>

// ---------------------------------------------------------------------------
// GraphEncoder: B=32 x N=128, E=128, H=8, DH=16, L=4, M=16384 edges.
// Round 12/13: revert edge phase to verified tbuild+contract (k_edge was 96us:
//   0.06 FLOP/B from L2, 96 barriers/block, 1 block/CU). Keep round-7 fusions:
//   k_setup (all prep + dist), k_lnqkv, k_loqkv(+next-layer QKV), 13 dispatches.
// Workspace: region A 15.2MB + T 48MB; qkv/oatt alias T (dead after contract).
// ---------------------------------------------------------------------------

typedef __attribute__((ext_vector_type(8))) short bf16x8;
typedef __attribute__((ext_vector_type(4))) float f32x4;
#define MFMA16(a, b, c) __builtin_amdgcn_mfma_f32_16x16x32_bf16(a, b, c, 0, 0, 0)

__device__ inline unsigned short f2bf(float f) {          // RTNE
  unsigned u = __float_as_uint(f);
  u = (u + 0x7FFF + ((u >> 16) & 1)) >> 16;
  return (unsigned short)u;
}
__device__ inline unsigned pack2(float a, float b) {
  return (unsigned)f2bf(a) | ((unsigned)f2bf(b) << 16);
}
__device__ inline float bf2f(unsigned short v) {
  return __uint_as_float(((unsigned)v) << 16);
}

// ---------------------------------------------------------------------------
// k_setup: blocks 0..2047 = node_proj (2 nodes/block); 2048..14335 = flat
// segments: zero agg | rbf | wb | qkvt+qkvb | wot | w1t | w2t | dist
// ---------------------------------------------------------------------------
__global__ __launch_bounds__(256) void k_setup(
    const float* __restrict__ x, const float* __restrict__ Wproj,
    const float* __restrict__ bproj, float* __restrict__ h,
    unsigned short* __restrict__ hb,
    const float* __restrict__ ea, float* __restrict__ ea2,
    const float* __restrict__ Wlin, const float* __restrict__ blin,
    unsigned short* __restrict__ wb,
    const float* __restrict__ Wq, const float* __restrict__ Wk,
    const float* __restrict__ Wv, const float* __restrict__ bq,
    const float* __restrict__ bk, const float* __restrict__ bv,
    unsigned short* __restrict__ qkvt, float* __restrict__ qkvb,
    const float* __restrict__ Wo, unsigned short* __restrict__ wot,
    const float* __restrict__ W1, unsigned short* __restrict__ w1t,
    const float* __restrict__ W2, unsigned short* __restrict__ w2t,
    float* __restrict__ agg,
    const float* __restrict__ pos, float* __restrict__ db) {
  __shared__ float xs[2][64];
  int blk = blockIdx.x, t = threadIdx.x;
  if (blk < 2048) {                       // ---- node projection ----
    int sub = t >> 7, e = t & 127;
    int n = blk * 2 + sub;
    if (e < 64) xs[sub][e] = x[n * 64 + e];
    __syncthreads();
    float acc = bproj[e];
#pragma unroll
    for (int a = 0; a < 64; a++) acc += xs[sub][a] * Wproj[a * 128 + e];
    h[n * 128 + e] = acc;
    hb[n * 128 + e] = f2bf(acc);
    return;
  }
  int idx = (blk - 2048) * 256 + t;       // 0 .. 3145727
  if (idx < 524288) { agg[idx] = 0.0f; return; }
  idx -= 524288;
  if (idx < 786432) {                     // ---- rbf/ea2 ----
    int m = idx / 48, c = idx % 48;
    float v;
    if (c < 15) {
      v = ea[m * 16 + c];
    } else if (c < 47) {
      int i = c - 15;
      float d = fminf(10.0f, fmaxf(0.0f, ea[m * 16 + 15]));
      float diff = d - 5.0f * (float)i / 31.0f;
      v = __expf(-38.44f * diff * diff);
    } else {
      v = 1.0f;
    }
    ea2[m * 48 + c] = v;
    return;
  }
  idx -= 786432;
  if (idx < 786432) {                     // ---- wb (Wlin+blin bf16) ----
    float v = (idx < 770048) ? Wlin[idx] : blin[idx - 770048];
    wb[idx] = f2bf(v);
    return;
  }
  idx -= 786432;
  if (idx < 196608) {                     // ---- qkvt + qkvb ----
    int l = idx / 49152, r = idx % 49152;
    int j = r / 128, a = r % 128;
    int jj = j & 127;
    const float* W = (j < 128) ? Wq : (j < 256) ? Wk : Wv;
    qkvt[idx] = f2bf(W[l * 16384 + a * 128 + jj]);
    if (a == 0) {
      const float* bb = (j < 128) ? bq : (j < 256) ? bk : bv;
      qkvb[l * 384 + j] = bb[l * 128 + jj];
    }
    return;
  }
  idx -= 196608;
  if (idx < 65536) {                      // ---- wot [l][128out][128k] ----
    int l = idx / 16384, r = idx % 16384;
    int a = r / 128, j = r % 128;
    wot[l * 16384 + j * 128 + a] = f2bf(Wo[idx]);
    return;
  }
  idx -= 65536;
  if (idx < 131072) {                     // ---- w1t [l][256out][128k] ----
    int l = idx / 32768, r = idx % 32768;
    int a = r / 256, j = r % 256;
    w1t[l * 32768 + j * 128 + a] = f2bf(W1[idx]);
    return;
  }
  idx -= 131072;
  if (idx < 131072) {                     // ---- w2t [l][128out][256k] ----
    int l = idx / 32768, r = idx % 32768;
    int a = r / 128, j = r % 128;
    w2t[l * 32768 + j * 256 + a] = f2bf(W2[idx]);
    return;
  }
  idx -= 131072;
  {                                       // ---- dist: db[b][i][j] ----
    int j = idx & 127, i2 = (idx >> 7) & 127, b = idx >> 14;
    float x0 = pos[(b * 128 + i2) * 3 + 0];
    float y0 = pos[(b * 128 + i2) * 3 + 1];
    float z0 = pos[(b * 128 + i2) * 3 + 2];
    float dx = x0 - pos[(b * 128 + j) * 3 + 0];
    float dy = y0 - pos[(b * 128 + j) * 3 + 1];
    float dz = z0 - pos[(b * 128 + j) * 3 + 2];
    float d2 = dx * dx + dy * dy + dz * dz;
    db[b * 16384 + i2 * 128 + j] = (d2 > 0.0f) ? sqrtf(d2) : 0.0f;
  }
}

// T[n][c][e] = sum_f hb[n,f] * wb[c][e*128+f]   (verified round 3)
__global__ __launch_bounds__(256) void k_tbuild(const unsigned short* __restrict__ hb,
    const unsigned short* __restrict__ wb, unsigned short* __restrict__ T) {
  __shared__ unsigned short hs[16384];
  __shared__ unsigned short wsm[16384];
  int c = blockIdx.x >> 5;
  int n0 = (blockIdx.x & 31) << 7;
  int t = threadIdx.x;
  const uint4* hg = (const uint4*)hb + n0 * 16;
  const uint4* wg = (const uint4*)wb + c * 2048;
  uint4* hs4 = (uint4*)hs;
  uint4* ws4 = (uint4*)wsm;
#pragma unroll
  for (int i = 0; i < 8; i++) {
    int q = t + i * 256;
    int row = q >> 4, ch = q & 15;
    int d = row * 16 + (ch ^ (row & 7));
    hs4[d] = hg[q];
    ws4[d] = wg[q];
  }
  __syncthreads();
  int w = t >> 6, l = t & 63;
  int lr = l & 15, lg = l >> 4;
  f32x4 acc[2][8];
#pragma unroll
  for (int et = 0; et < 2; et++)
#pragma unroll
    for (int n = 0; n < 8; n++) acc[et][n] = (f32x4){0.f, 0.f, 0.f, 0.f};
#pragma unroll
  for (int s = 0; s < 4; s++) {
    bf16x8 af[2];
#pragma unroll
    for (int et = 0; et < 2; et++) {
      int er = w * 32 + et * 16 + lr;
      int ch = (s * 4 + lg) ^ (er & 7);
      af[et] = *(const bf16x8*)&wsm[(er * 16 + ch) * 8];
    }
#pragma unroll
    for (int n = 0; n < 8; n++) {
      int nr = n * 16 + lr;
      int ch = (s * 4 + lg) ^ (nr & 7);
      bf16x8 bfr = *(const bf16x8*)&hs[(nr * 16 + ch) * 8];
      acc[0][n] = MFMA16(af[0], bfr, acc[0][n]);
      acc[1][n] = MFMA16(af[1], bfr, acc[1][n]);
    }
  }
#pragma unroll
  for (int et = 0; et < 2; et++)
#pragma unroll
    for (int n = 0; n < 8; n++) {
      int node = n0 + n * 16 + lr;
      int e0 = w * 32 + et * 16 + lg * 4;
      uint2 pk;
      pk.x = pack2(acc[et][n][0], acc[et][n][1]);
      pk.y = pack2(acc[et][n][2], acc[et][n][3]);
      *(uint2*)&T[node * 6144 + c * 128 + e0] = pk;
    }
}

// msg[m,e] = sum_c ea2[m,c]*T[src][c][e]; atomicAdd agg[dst,e]  (verified r3)
__global__ __launch_bounds__(128) void k_contract(const float* __restrict__ ea2,
    const int* __restrict__ ei, const unsigned short* __restrict__ T,
    float* __restrict__ agg) {
  int m = blockIdx.x, e = threadIdx.x;
  int src = ei[16384 + m], dst = ei[m];
  __shared__ float ec[48];
  if (e < 48) ec[e] = ea2[m * 48 + e];
  __syncthreads();
  const unsigned short* Ts = T + src * 6144;
  float acc = 0.0f;
#pragma unroll 6
  for (int c = 0; c < 48; c++) acc += ec[c] * bf2f(Ts[c * 128 + e]);
  atomicAdd(&agg[dst * 128 + e], acc);
}

// ---------------------------------------------------------------------------
// k_lnqkv: xp = LN(agg + hbuf; g_en,b_en)  then  qkv = xp @ qkvt^T + qkvb
// ---------------------------------------------------------------------------
__global__ __launch_bounds__(256) void k_lnqkv(const float* __restrict__ agg,
    const float* __restrict__ hbuf, const float* __restrict__ g_en,
    const float* __restrict__ b_en, float* __restrict__ xp,
    const unsigned short* __restrict__ qkvt, const float* __restrict__ qkvb,
    float* __restrict__ qkv) {
  __shared__ unsigned short As[8192];    // [64][128] bf16 swizzled
  __shared__ unsigned short Bs[16384];
  int t = threadIdx.x, m0 = blockIdx.x * 64;
  int w = t >> 6, l = t & 63, lr = l & 15, lg = l >> 4;
  float ge0 = g_en[2 * l], ge1 = g_en[2 * l + 1];
  float be0 = b_en[2 * l], be1 = b_en[2 * l + 1];
  for (int i = 0; i < 16; i++) {
    int r = i * 4 + w;
    float2 av = ((const float2*)(agg + (size_t)(m0 + r) * 128))[l];
    float2 hv = ((const float2*)(hbuf + (size_t)(m0 + r) * 128))[l];
    float v0 = av.x + hv.x, v1 = av.y + hv.y;
    float s = v0 + v1, s2 = v0 * v0 + v1 * v1;
#pragma unroll
    for (int o = 1; o < 64; o <<= 1) { s += __shfl_xor(s, o); s2 += __shfl_xor(s2, o); }
    float mu = s * (1.0f / 128.0f);
    float var = fmaxf(s2 * (1.0f / 128.0f) - mu * mu, 0.0f);
    float inv = rsqrtf(var + 1e-5f);
    float o0 = (v0 - mu) * inv * ge0 + be0;
    float o1 = (v1 - mu) * inv * ge1 + be1;
    ((float2*)(xp + (size_t)(m0 + r) * 128))[l] = make_float2(o0, o1);
    ((unsigned*)As)[(r * 16 + ((l >> 2) ^ (r & 7))) * 4 + (l & 3)] = pack2(o0, o1);
  }
  uint4* Bs4 = (uint4*)Bs;
  for (int cchunk = 0; cchunk < 3; cchunk++) {
    __syncthreads();
#pragma unroll
    for (int i = 0; i < 8; i++) {
      int q = t + i * 256;
      int row = q >> 4, ch = q & 15;
      Bs4[row * 16 + (ch ^ (row & 7))] =
          ((const uint4*)(qkvt + (size_t)(cchunk * 128 + row) * 128))[ch];
    }
    __syncthreads();
    f32x4 acc[2][4];
#pragma unroll
    for (int e2 = 0; e2 < 2; e2++)
#pragma unroll
      for (int n = 0; n < 4; n++) acc[e2][n] = (f32x4){0.f, 0.f, 0.f, 0.f};
#pragma unroll
    for (int s = 0; s < 4; s++) {
      bf16x8 af[2];
#pragma unroll
      for (int e2 = 0; e2 < 2; e2++) {
        int er = w * 32 + e2 * 16 + lr;
        int ch = (s * 4 + lg) ^ (er & 7);
        af[e2] = *(const bf16x8*)&Bs[(er * 16 + ch) * 8];
      }
#pragma unroll
      for (int n = 0; n < 4; n++) {
        int nr = n * 16 + lr;
        int ch = (s * 4 + lg) ^ (nr & 7);
        bf16x8 bfr = *(const bf16x8*)&As[(nr * 16 + ch) * 8];
        acc[0][n] = MFMA16(af[0], bfr, acc[0][n]);
        acc[1][n] = MFMA16(af[1], bfr, acc[1][n]);
      }
    }
#pragma unroll
    for (int e2 = 0; e2 < 2; e2++) {
      int e0 = cchunk * 128 + w * 32 + e2 * 16 + lg * 4;
      float4 bb = *(const float4*)&qkvb[e0];
#pragma unroll
      for (int n = 0; n < 4; n++) {
        int node = m0 + n * 16 + lr;
        float4 ov;
#pragma unroll
        for (int r = 0; r < 4; r++) ((float*)&ov)[r] = acc[e2][n][r] + ((const float*)&bb)[r];
        *(float4*)&qkv[(size_t)node * 384 + e0] = ov;
      }
    }
  }
}

// attention for one (b,h); qkv packed [node][384] = q|k|v (verified round 5)
__global__ __launch_bounds__(128) void k_attn(const float* __restrict__ qkv,
    const float* __restrict__ db, float* __restrict__ oatt) {
  __shared__ float ks[128][16], vs[128][16];
  int bh = blockIdx.x, b = bh >> 3, h = bh & 7;
  int i = threadIdx.x;
  int node = b * 128 + i;
  const float4* kr = (const float4*)(qkv + (size_t)node * 384 + 128 + h * 16);
  const float4* vr = (const float4*)(qkv + (size_t)node * 384 + 256 + h * 16);
#pragma unroll
  for (int d4 = 0; d4 < 4; d4++) {
    *(float4*)&ks[i][d4 * 4] = kr[d4];
    *(float4*)&vs[i][d4 * 4] = vr[d4];
  }
  float qr[16];
  const float4* qp = (const float4*)(qkv + (size_t)node * 384 + h * 16);
#pragma unroll
  for (int d4 = 0; d4 < 4; d4++) *(float4*)&qr[d4 * 4] = qp[d4];
  __syncthreads();
  const float4* dbr = (const float4*)(db + b * 16384 + i * 128);
  float rsum = 0.0f, o[16] = {};
  for (int j4 = 0; j4 < 32; j4++) {
    float4 dv = dbr[j4];
#pragma unroll
    for (int u = 0; u < 4; u++) {
      int j = j4 * 4 + u;
      float s = 0.0f;
#pragma unroll
      for (int d = 0; d < 16; d++) s += qr[d] * ks[j][d];
      s = s * 0.25f + ((const float*)&dv)[u];
      s = fminf(10.0f, fmaxf(-10.0f, s));
      float p = __expf(s);
      rsum += p;
#pragma unroll
      for (int d = 0; d < 16; d++) o[d] += p * vs[j][d];
    }
  }
  float r = 1.0f / rsum;
  float* op = oatt + (size_t)node * 128 + h * 16;
#pragma unroll
  for (int d4 = 0; d4 < 4; d4++)
    *(float4*)&op[d4 * 4] = make_float4(o[d4 * 4] * r, o[d4 * 4 + 1] * r, o[d4 * 4 + 2] * r, o[d4 * 4 + 3] * r);
}

// ---------------------------------------------------------------------------
// k_loqkv: layerout (verified round 6) with optional next-layer QKV tail.
// ---------------------------------------------------------------------------
template <int QKV>
__global__ __launch_bounds__(256) void k_loqkv(
    const float* __restrict__ oatt, float* __restrict__ xp,
    const unsigned short* __restrict__ wot, const float* __restrict__ bo,
    const float* __restrict__ g1, const float* __restrict__ b1,
    const unsigned short* __restrict__ w1t, const float* __restrict__ bf1,
    const unsigned short* __restrict__ w2t, const float* __restrict__ bf2,
    const float* __restrict__ g2, const float* __restrict__ b2,
    const unsigned short* __restrict__ qkvtn, const float* __restrict__ qkvbn,
    float* __restrict__ qkv) {
  __shared__ unsigned short ffs[16384];   // [64][32ch][8]; ph1: A-stage
  __shared__ unsigned short x1s[8192];    // [64][16ch][8]; later: xp bf16 stage
  __shared__ unsigned short Bs[16384];
  __shared__ float red[2][4][64];
  int t = threadIdx.x;
  int m0 = blockIdx.x << 6;
  int w = t >> 6, l = t & 63, lr = l & 15, lg = l >> 4;

  // ---- phase 1: Wo GEMM ----
  {
    uint4* a4 = (uint4*)ffs;
#pragma unroll
    for (int i = 0; i < 4; i++) {
      int q = t + i * 256;
      int row = q >> 4, ch = q & 15;
      const float* ap = oatt + (size_t)(m0 + row) * 128 + ch * 8;
      float4 fa = *(const float4*)ap;
      float4 fb = *(const float4*)(ap + 4);
      uint4 pk;
      pk.x = pack2(fa.x, fa.y); pk.y = pack2(fa.z, fa.w);
      pk.z = pack2(fb.x, fb.y); pk.w = pack2(fb.z, fb.w);
      a4[row * 16 + (ch ^ (row & 7))] = pk;
    }
    uint4* b4p = (uint4*)Bs;
#pragma unroll
    for (int i = 0; i < 8; i++) {
      int q = t + i * 256;
      int row = q >> 4, ch = q & 15;
      b4p[row * 16 + (ch ^ (row & 7))] = *((const uint4*)(wot + (size_t)row * 128) + ch);
    }
  }
  __syncthreads();
  f32x4 acc[2][4];
#pragma unroll
  for (int et = 0; et < 2; et++)
#pragma unroll
    for (int n = 0; n < 4; n++) acc[et][n] = (f32x4){0.f, 0.f, 0.f, 0.f};
#pragma unroll
  for (int s = 0; s < 4; s++) {
    bf16x8 af[2];
#pragma unroll
    for (int et = 0; et < 2; et++) {
      int er = w * 32 + et * 16 + lr;
      int ch = (s * 4 + lg) ^ (er & 7);
      af[et] = *(const bf16x8*)&Bs[(er * 16 + ch) * 8];
    }
#pragma unroll
    for (int n = 0; n < 4; n++) {
      int nr = n * 16 + lr;
      int ch = (s * 4 + lg) ^ (nr & 7);
      bf16x8 bfr = *(const bf16x8*)&ffs[(nr * 16 + ch) * 8];
      acc[0][n] = MFMA16(af[0], bfr, acc[0][n]);
      acc[1][n] = MFMA16(af[1], bfr, acc[1][n]);
    }
  }
  // epilogue 1: + bo + xp residual -> LN(g1,b1) -> v1 regs + x1s bf16
  float v1[2][4][4];
  {
    int e0 = w * 32 + lg * 4;
    float4 bo4[2] = { *(const float4*)&bo[e0], *(const float4*)&bo[e0 + 16] };
#pragma unroll
    for (int et = 0; et < 2; et++)
#pragma unroll
      for (int n = 0; n < 4; n++) {
        int node = m0 + n * 16 + lr;
        float4 rv = *(const float4*)&xp[(size_t)node * 128 + e0 + et * 16];
#pragma unroll
        for (int r = 0; r < 4; r++)
          v1[et][n][r] = acc[et][n][r] + ((const float*)&bo4[et])[r] + ((const float*)&rv)[r];
      }
    float s[4], s2[4];
#pragma unroll
    for (int n = 0; n < 4; n++) {
      float a = 0, b2s = 0;
#pragma unroll
      for (int et = 0; et < 2; et++)
#pragma unroll
        for (int r = 0; r < 4; r++) { a += v1[et][n][r]; b2s += v1[et][n][r] * v1[et][n][r]; }
      s[n] = a; s2[n] = b2s;
    }
#pragma unroll
    for (int off = 16; off < 64; off <<= 1)
#pragma unroll
      for (int n = 0; n < 4; n++) { s[n] += __shfl_xor(s[n], off); s2[n] += __shfl_xor(s2[n], off); }
    if (l < 16) {
#pragma unroll
      for (int n = 0; n < 4; n++) { red[0][w][n * 16 + lr] = s[n]; red[1][w][n * 16 + lr] = s2[n]; }
    }
    __syncthreads();
    float4 g4[2] = { *(const float4*)&g1[e0], *(const float4*)&g1[e0 + 16] };
    float4 bb4[2] = { *(const float4*)&b1[e0], *(const float4*)&b1[e0 + 16] };
#pragma unroll
    for (int n = 0; n < 4; n++) {
      int nloc = n * 16 + lr;
      float ts  = red[0][0][nloc] + red[0][1][nloc] + red[0][2][nloc] + red[0][3][nloc];
      float ts2 = red[1][0][nloc] + red[1][1][nloc] + red[1][2][nloc] + red[1][3][nloc];
      float mu = ts * (1.0f / 128.0f);
      float var = fmaxf(ts2 * (1.0f / 128.0f) - mu * mu, 0.0f);
      float inv = rsqrtf(var + 1e-5f);
#pragma unroll
      for (int et = 0; et < 2; et++) {
#pragma unroll
        for (int r = 0; r < 4; r++)
          v1[et][n][r] = (v1[et][n][r] - mu) * inv * ((const float*)&g4[et])[r] + ((const float*)&bb4[et])[r];
        int ch = w * 4 + et * 2 + (lg >> 1);
        uint2 pk;
        pk.x = pack2(v1[et][n][0], v1[et][n][1]);
        pk.y = pack2(v1[et][n][2], v1[et][n][3]);
        *(uint2*)&x1s[(nloc * 16 + (ch ^ (nloc & 7))) * 8 + (lg & 1) * 4] = pk;
      }
    }
  }
  __syncthreads();

  // ---- phase 2: FFN1 (two 128-col tiles), relu -> ffs ----
  for (int ct = 0; ct < 2; ct++) {
    if (ct) __syncthreads();
    uint4* b4p = (uint4*)Bs;
#pragma unroll
    for (int i = 0; i < 8; i++) {
      int q = t + i * 256;
      int row = q >> 4, ch = q & 15;
      b4p[row * 16 + (ch ^ (row & 7))] =
          *((const uint4*)(w1t + (size_t)(ct * 128 + row) * 128) + ch);
    }
    __syncthreads();
#pragma unroll
    for (int et = 0; et < 2; et++)
#pragma unroll
      for (int n = 0; n < 4; n++) acc[et][n] = (f32x4){0.f, 0.f, 0.f, 0.f};
#pragma unroll
    for (int s = 0; s < 4; s++) {
      bf16x8 af[2];
#pragma unroll
      for (int et = 0; et < 2; et++) {
        int er = w * 32 + et * 16 + lr;
        int ch = (s * 4 + lg) ^ (er & 7);
        af[et] = *(const bf16x8*)&Bs[(er * 16 + ch) * 8];
      }
#pragma unroll
      for (int n = 0; n < 4; n++) {
        int nr = n * 16 + lr;
        int ch = (s * 4 + lg) ^ (nr & 7);
        bf16x8 bfr = *(const bf16x8*)&x1s[(nr * 16 + ch) * 8];
        acc[0][n] = MFMA16(af[0], bfr, acc[0][n]);
        acc[1][n] = MFMA16(af[1], bfr, acc[1][n]);
      }
    }
    int e0 = w * 32 + lg * 4;
    float4 bb0 = *(const float4*)&bf1[ct * 128 + e0];
    float4 bb1 = *(const float4*)&bf1[ct * 128 + e0 + 16];
#pragma unroll
    for (int et = 0; et < 2; et++) {
      const float* bbp = et ? (const float*)&bb1 : (const float*)&bb0;
#pragma unroll
      for (int n = 0; n < 4; n++) {
        int nloc = n * 16 + lr;
        float f0 = fmaxf(acc[et][n][0] + bbp[0], 0.0f);
        float f1 = fmaxf(acc[et][n][1] + bbp[1], 0.0f);
        float f2 = fmaxf(acc[et][n][2] + bbp[2], 0.0f);
        float f3 = fmaxf(acc[et][n][3] + bbp[3], 0.0f);
        int cg = ct * 16 + w * 4 + et * 2 + (lg >> 1);
        uint2 pk;
        pk.x = pack2(f0, f1);
        pk.y = pack2(f2, f3);
        *(uint2*)&ffs[(nloc * 32 + (cg ^ (nloc & 7))) * 8 + (lg & 1) * 4] = pk;
      }
    }
  }
  __syncthreads();

  // ---- phase 3: FFN2 (K=256) + bf2 + x1 res + LN(g2,b2) -> xp (+x1s pack) --
  f32x4 acc3[2][4];
#pragma unroll
  for (int et = 0; et < 2; et++)
#pragma unroll
    for (int n = 0; n < 4; n++) acc3[et][n] = (f32x4){0.f, 0.f, 0.f, 0.f};
  for (int kc = 0; kc < 2; kc++) {
    if (kc) __syncthreads();
    uint4* b4p = (uint4*)Bs;
#pragma unroll
    for (int i = 0; i < 8; i++) {
      int q = t + i * 256;
      int row = q >> 4, ch = q & 15;
      b4p[row * 16 + (ch ^ (row & 7))] =
          *((const uint4*)(w2t + (size_t)row * 256 + kc * 128) + ch);
    }
    __syncthreads();
#pragma unroll
    for (int s = 0; s < 4; s++) {
      bf16x8 af[2];
#pragma unroll
      for (int et = 0; et < 2; et++) {
        int er = w * 32 + et * 16 + lr;
        int ch = (s * 4 + lg) ^ (er & 7);
        af[et] = *(const bf16x8*)&Bs[(er * 16 + ch) * 8];
      }
#pragma unroll
      for (int n = 0; n < 4; n++) {
        int nr = n * 16 + lr;
        int gch = kc * 16 + s * 4 + lg;
        bf16x8 bfr = *(const bf16x8*)&ffs[(nr * 32 + (gch ^ (nr & 7))) * 8];
        acc3[0][n] = MFMA16(af[0], bfr, acc3[0][n]);
        acc3[1][n] = MFMA16(af[1], bfr, acc3[1][n]);
      }
    }
  }
  {
    int e0 = w * 32 + lg * 4;
    float4 bo4[2] = { *(const float4*)&bf2[e0], *(const float4*)&bf2[e0 + 16] };
    float v2[2][4][4];
#pragma unroll
    for (int et = 0; et < 2; et++)
#pragma unroll
      for (int n = 0; n < 4; n++)
#pragma unroll
        for (int r = 0; r < 4; r++)
          v2[et][n][r] = acc3[et][n][r] + ((const float*)&bo4[et])[r] + v1[et][n][r];
    float s[4], s2[4];
#pragma unroll
    for (int n = 0; n < 4; n++) {
      float a = 0, b2s = 0;
#pragma unroll
      for (int et = 0; et < 2; et++)
#pragma unroll
        for (int r = 0; r < 4; r++) { a += v2[et][n][r]; b2s += v2[et][n][r] * v2[et][n][r]; }
      s[n] = a; s2[n] = b2s;
    }
#pragma unroll
    for (int off = 16; off < 64; off <<= 1)
#pragma unroll
      for (int n = 0; n < 4; n++) { s[n] += __shfl_xor(s[n], off); s2[n] += __shfl_xor(s2[n], off); }
    __syncthreads();
    if (l < 16) {
#pragma unroll
      for (int n = 0; n < 4; n++) { red[0][w][n * 16 + lr] = s[n]; red[1][w][n * 16 + lr] = s2[n]; }
    }
    __syncthreads();
    float4 g4[2] = { *(const float4*)&g2[e0], *(const float4*)&g2[e0 + 16] };
    float4 bb4[2] = { *(const float4*)&b2[e0], *(const float4*)&b2[e0 + 16] };
#pragma unroll
    for (int n = 0; n < 4; n++) {
      int nloc = n * 16 + lr;
      float ts  = red[0][0][nloc] + red[0][1][nloc] + red[0][2][nloc] + red[0][3][nloc];
      float ts2 = red[1][0][nloc] + red[1][1][nloc] + red[1][2][nloc] + red[1][3][nloc];
      float mu = ts * (1.0f / 128.0f);
      float var = fmaxf(ts2 * (1.0f / 128.0f) - mu * mu, 0.0f);
      float inv = rsqrtf(var + 1e-5f);
      int node = m0 + nloc;
#pragma unroll
      for (int et = 0; et < 2; et++) {
        float4 ov;
#pragma unroll
        for (int r = 0; r < 4; r++)
          ((float*)&ov)[r] = (v2[et][n][r] - mu) * inv * ((const float*)&g4[et])[r] + ((const float*)&bb4[et])[r];
        *(float4*)&xp[(size_t)node * 128 + e0 + et * 16] = ov;
        if (QKV) {
          int ch = w * 4 + et * 2 + (lg >> 1);
          uint2 pk;
          pk.x = pack2(((float*)&ov)[0], ((float*)&ov)[1]);
          pk.y = pack2(((float*)&ov)[2], ((float*)&ov)[3]);
          *(uint2*)&x1s[(nloc * 16 + (ch ^ (nloc & 7))) * 8 + (lg & 1) * 4] = pk;
        }
      }
    }
  }

  if (QKV) {
    // ---- phase 4: next-layer QKV from x1s (xp bf16) ----
    uint4* Bs4 = (uint4*)Bs;
    for (int cchunk = 0; cchunk < 3; cchunk++) {
      __syncthreads();
#pragma unroll
      for (int i = 0; i < 8; i++) {
        int q = t + i * 256;
        int row = q >> 4, ch = q & 15;
        Bs4[row * 16 + (ch ^ (row & 7))] =
            ((const uint4*)(qkvtn + (size_t)(cchunk * 128 + row) * 128))[ch];
      }
      __syncthreads();
      f32x4 qa[2][4];
#pragma unroll
      for (int e2 = 0; e2 < 2; e2++)
#pragma unroll
        for (int n = 0; n < 4; n++) qa[e2][n] = (f32x4){0.f, 0.f, 0.f, 0.f};
#pragma unroll
      for (int s = 0; s < 4; s++) {
        bf16x8 af[2];
#pragma unroll
        for (int e2 = 0; e2 < 2; e2++) {
          int er = w * 32 + e2 * 16 + lr;
          int ch = (s * 4 + lg) ^ (er & 7);
          af[e2] = *(const bf16x8*)&Bs[(er * 16 + ch) * 8];
        }
#pragma unroll
        for (int n = 0; n < 4; n++) {
          int nr = n * 16 + lr;
          int ch = (s * 4 + lg) ^ (nr & 7);
          bf16x8 bfr = *(const bf16x8*)&x1s[(nr * 16 + ch) * 8];
          qa[0][n] = MFMA16(af[0], bfr, qa[0][n]);
          qa[1][n] = MFMA16(af[1], bfr, qa[1][n]);
        }
      }
#pragma unroll
      for (int e2 = 0; e2 < 2; e2++) {
        int e0 = cchunk * 128 + w * 32 + e2 * 16 + lg * 4;
        float4 bb = *(const float4*)&qkvbn[e0];
#pragma unroll
        for (int n = 0; n < 4; n++) {
          int node = m0 + n * 16 + lr;
          float4 ov;
#pragma unroll
          for (int r = 0; r < 4; r++) ((float*)&ov)[r] = qa[e2][n][r] + ((const float*)&bb)[r];
          *(float4*)&qkv[(size_t)node * 384 + e0] = ov;
        }
      }
    }
  }
}

__global__ __launch_bounds__(128) void k_pool(const float* __restrict__ xp, float* __restrict__ out) {
  int b = blockIdx.x, e = threadIdx.x;
  float s = 0.0f;
  for (int n = 0; n < 128; n++) s += xp[(b * 128 + n) * 128 + e];
  out[b * 128 + e] = s * (1.0f / 128.0f);
}

extern "C" void kernel_launch(void* const* d_in, const int* in_sizes, int n_in,
                              void* d_out, int out_size, void* d_ws, size_t ws_size,
                              hipStream_t stream) {
  const float* x     = (const float*)d_in[0];
  const int*   ei    = (const int*)  d_in[1];
  const float* ea    = (const float*)d_in[2];
  const float* pos   = (const float*)d_in[3];
  const float* Wproj = (const float*)d_in[5];
  const float* bproj = (const float*)d_in[6];
  const float* Wlin  = (const float*)d_in[7];
  const float* blin  = (const float*)d_in[8];
  const float* g_en  = (const float*)d_in[9];
  const float* b_en  = (const float*)d_in[10];
  const float* Wq    = (const float*)d_in[11];
  const float* Wk    = (const float*)d_in[12];
  const float* Wv    = (const float*)d_in[13];
  const float* Wo    = (const float*)d_in[14];
  const float* bq    = (const float*)d_in[15];
  const float* bk    = (const float*)d_in[16];
  const float* bv    = (const float*)d_in[17];
  const float* bo    = (const float*)d_in[18];
  const float* g1    = (const float*)d_in[19];
  const float* b1    = (const float*)d_in[20];
  const float* W1    = (const float*)d_in[21];
  const float* bf1   = (const float*)d_in[22];
  const float* W2    = (const float*)d_in[23];
  const float* bf2   = (const float*)d_in[24];
  const float* g2    = (const float*)d_in[25];
  const float* b2    = (const float*)d_in[26];

  float* ws = (float*)d_ws;
  // region A (written by k_setup; live through edge phase): 15.2 MB
  float* ea2  = ws;                                         // 786432 f
  float* hbuf = ea2  + 786432;                              // 524288 f
  float* agg  = hbuf + 524288;                              // 524288 f
  unsigned short* hbf  = (unsigned short*)(agg + 524288);   // 524288 us
  unsigned short* wbf  = hbf + 524288;                      // 786432 us
  unsigned short* qkvt = wbf + 786432;                      // 196608 us
  unsigned short* wot  = qkvt + 196608;                     // 65536 us
  unsigned short* w1t  = wot + 65536;                       // 131072 us
  unsigned short* w2t  = w1t + 131072;                      // 131072 us
  float* qkvb = (float*)(w2t + 131072);                     // 1536 f
  float* db   = qkvb + 1536;                                // 524288 f (pre-T write)
  float* xp   = db   + 524288;                              // 524288 f
  // region B: T [4096][48][128] bf16 = 48 MB (dead after k_contract)
  float* Tf = xp + 524288;
  unsigned short* Tb = (unsigned short*)Tf;
  // region C aliases T (first written after contract)
  float* qkv  = Tf;                    // 1572864 f
  float* oatt = qkv + 1572864;         // 524288 f

  k_setup<<<14336, 256, 0, stream>>>(x, Wproj, bproj, hbuf, hbf,
      ea, ea2, Wlin, blin, wbf, Wq, Wk, Wv, bq, bk, bv, qkvt, qkvb,
      Wo, wot, W1, w1t, W2, w2t, agg, pos, db);
  k_tbuild<<<1536, 256, 0, stream>>>(hbf, wbf, Tb);
  k_contract<<<16384, 128, 0, stream>>>(ea2, ei, Tb, agg);
  k_lnqkv<<<64, 256, 0, stream>>>(agg, hbuf, g_en, b_en, xp, qkvt, qkvb, qkv);

  for (int l = 0; l < 4; l++) {
    k_attn<<<256, 128, 0, stream>>>(qkv, db, oatt);
    if (l < 3) {
      k_loqkv<1><<<64, 256, 0, stream>>>(oatt, xp,
          wot + l * 16384, bo + l * 128, g1 + l * 128, b1 + l * 128,
          w1t + l * 32768, bf1 + l * 256,
          w2t + l * 32768, bf2 + l * 128, g2 + l * 128, b2 + l * 128,
          qkvt + (l + 1) * 49152, qkvb + (l + 1) * 384, qkv);
    } else {
      k_loqkv<0><<<64, 256, 0, stream>>>(oatt, xp,
          wot + l * 16384, bo + l * 128, g1 + l * 128, b1 + l * 128,
          w1t + l * 32768, bf1 + l * 256,
          w2t + l * 32768, bf2 + l * 128, g2 + l * 128, b2 + l * 128,
          nullptr, nullptr, nullptr);
    }
  }

  k_pool<<<32, 128, 0, stream>>>(xp, (float*)d_out);
}